// Round 1
// baseline (688.571 us; speedup 1.0000x reference)
//
#include <hip/hip_runtime.h>
#include <cstdint>
#include <cstddef>

// Problem constants
#define MROWS 8192   // B*C = 32*256
#define VIN   6890   // K (real)
#define VOUT  1723   // N (real)
#define KP    6912   // K padded to multiple of 32 (216 * 32)
#define NP    1792   // N padded to multiple of 128 (14 * 128)

typedef __attribute__((ext_vector_type(8))) __bf16 bf16x8;  // 4 VGPRs, A/B frag
typedef __attribute__((ext_vector_type(4))) float f32x4;    // C/D frag

// ---------------- fp32 -> bf16 (RNE) ----------------
__device__ __forceinline__ uint16_t f2bf(float f) {
    uint32_t u = __builtin_bit_cast(uint32_t, f);
    u += 0x7fffu + ((u >> 16) & 1u);
    return (uint16_t)(u >> 16);
}

// x: [MROWS][VIN] fp32 -> xb: [MROWS][KP] bf16 (zero-padded K tail)
__global__ void cvt_x_kernel(const float* __restrict__ x, uint16_t* __restrict__ xb) {
    const int row = blockIdx.y;
    const int cp  = blockIdx.x * blockDim.x + threadIdx.x;   // column pair
    if (cp >= KP / 2) return;
    const int c = cp * 2;
    uint32_t v = 0;
    if (c < VIN) {  // VIN even, so pairs are either fully valid or fully pad
        const float2 f = *(const float2*)(x + (size_t)row * VIN + c);
        v = (uint32_t)f2bf(f.x) | ((uint32_t)f2bf(f.y) << 16);
    }
    *(uint32_t*)(xb + (size_t)row * KP + c) = v;
}

// M: [VOUT][VIN] fp32 -> mb: [NP][KP] bf16 (zero-padded rows & K tail)
__global__ void cvt_m_kernel(const float* __restrict__ m, uint16_t* __restrict__ mb) {
    const int row = blockIdx.y;
    const int cp  = blockIdx.x * blockDim.x + threadIdx.x;
    if (cp >= KP / 2) return;
    const int c = cp * 2;
    uint32_t v = 0;
    if (row < VOUT && c < VIN) {
        const float2 f = *(const float2*)(m + (size_t)row * VIN + c);
        v = (uint32_t)f2bf(f.x) | ((uint32_t)f2bf(f.y) << 16);
    }
    *(uint32_t*)(mb + (size_t)row * KP + c) = v;
}

// ---------------- async global -> LDS, 16B/lane ----------------
__device__ __forceinline__ void gload_lds16(const void* g, void* l) {
    __builtin_amdgcn_global_load_lds(
        (const __attribute__((address_space(1))) void*)g,
        (__attribute__((address_space(3))) void*)l,
        16, 0, 0);
}

// ---------------- bf16 MFMA GEMM: C[m,n] = sum_k X[m,k] * W[n,k] ----------------
// m97 structure: 128x128 tile, 4 waves in 2x2, each wave 4x4 of 16x16x32 MFMA,
// BK=32 staging via global_load_lds (16B), 2-barrier K-loop.
__global__ __launch_bounds__(256) void gemm_bt_kernel(
        const uint16_t* __restrict__ X,    // [MROWS][KP] bf16 bits
        const uint16_t* __restrict__ W,    // [NP][KP]   bf16 bits
        float* __restrict__ out) {         // [MROWS][VOUT] fp32
    __shared__ uint16_t lsA[128 * 32];  // 8 KB
    __shared__ uint16_t lsB[128 * 32];  // 8 KB

    const int t    = threadIdx.x;
    const int wave = t >> 6;
    const int lane = t & 63;
    const int wm   = wave >> 1;   // 0..1
    const int wn   = wave & 1;    // 0..1
    const int bm   = blockIdx.y;  // 0..63  (M tiles)
    const int bn   = blockIdx.x;  // 0..13  (N tiles)

    // staging coords: 256 threads cover 64 rows x 64 bytes per issue
    const int srow  = t >> 2;              // 0..63
    const int sbyte = (t & 3) * 16;        // 0/16/32/48 within 64B (=32 bf16) row

    const char* gA = (const char*)(X + (size_t)(bm * 128 + srow) * KP) + sbyte;
    const char* gB = (const char*)(W + (size_t)(bn * 128 + srow) * KP) + sbyte;
    const size_t gRow64 = (size_t)64 * KP * 2;  // 64 rows in bytes

    // wave-uniform LDS bases (global_load_lds scatters at base + lane*16)
    uint16_t* lA0 = &lsA[wave * 512];
    uint16_t* lA1 = &lsA[2048 + wave * 512];
    uint16_t* lB0 = &lsB[wave * 512];
    uint16_t* lB1 = &lsB[2048 + wave * 512];

    // compute coords (16x16x32 A/B frag: row/col = lane&15, k = (lane>>4)*8 + j)
    const int m15 = lane & 15;
    const int kq  = (lane >> 4) * 8;   // ushort offset within 32-elem row

    f32x4 acc[4][4] = {};

    for (int kb = 0; kb < KP / 32; ++kb) {
        const size_t koff = (size_t)kb * 64;  // bytes
        gload_lds16(gA + koff,          lA0);
        gload_lds16(gA + gRow64 + koff, lA1);
        gload_lds16(gB + koff,          lB0);
        gload_lds16(gB + gRow64 + koff, lB1);
        __syncthreads();  // compiler emits s_waitcnt vmcnt(0) before s_barrier

        bf16x8 a[4], b[4];
#pragma unroll
        for (int i = 0; i < 4; ++i) {
            a[i] = *(const bf16x8*)&lsA[(wm * 64 + i * 16 + m15) * 32 + kq];
            b[i] = *(const bf16x8*)&lsB[(wn * 64 + i * 16 + m15) * 32 + kq];
        }
#pragma unroll
        for (int i = 0; i < 4; ++i)
#pragma unroll
            for (int j = 0; j < 4; ++j)
                acc[i][j] = __builtin_amdgcn_mfma_f32_16x16x32_bf16(
                    a[i], b[j], acc[i][j], 0, 0, 0);
        __syncthreads();
    }

    // epilogue: C/D layout col = lane&15, row = (lane>>4)*4 + reg  [m89/m91 verified]
    const int row0 = bm * 128 + wm * 64 + (lane >> 4) * 4;
    const int col0 = bn * 128 + wn * 64 + m15;
#pragma unroll
    for (int j = 0; j < 4; ++j) {
        const int col = col0 + j * 16;
        if (col < VOUT) {
#pragma unroll
            for (int i = 0; i < 4; ++i) {
                const int rowb = row0 + i * 16;
#pragma unroll
                for (int r = 0; r < 4; ++r)
                    out[(size_t)(rowb + r) * VOUT + col] = acc[i][j][r];
            }
        }
    }
}

// ---------------- fp32 fallback (only if ws too small) ----------------
__global__ void fallback_kernel(const float* __restrict__ x,
                                const float* __restrict__ M,
                                float* __restrict__ out) {
    const int m = blockIdx.y;
    const int o = blockIdx.x * blockDim.x + threadIdx.x;
    if (o >= VOUT) return;
    const float* xr = x + (size_t)m * VIN;
    const float* mr = M + (size_t)o * VIN;
    float s = 0.f;
    for (int k = 0; k < VIN; ++k) s = fmaf(xr[k], mr[k], s);
    out[(size_t)m * VOUT + o] = s;
}

extern "C" void kernel_launch(void* const* d_in, const int* in_sizes, int n_in,
                              void* d_out, int out_size, void* d_ws, size_t ws_size,
                              hipStream_t stream) {
    const float* x = (const float*)d_in[0];
    const float* M = (const float*)d_in[1];
    float* out = (float*)d_out;

    const size_t need = ((size_t)MROWS * KP + (size_t)NP * KP) * sizeof(uint16_t);
    if (ws_size < need) {
        // emergency correct-but-slow path
        fallback_kernel<<<dim3((VOUT + 255) / 256, MROWS), dim3(256), 0, stream>>>(x, M, out);
        return;
    }

    uint16_t* xb = (uint16_t*)d_ws;
    uint16_t* mb = xb + (size_t)MROWS * KP;

    const dim3 cblk(256);
    cvt_x_kernel<<<dim3((KP / 2 + 255) / 256, MROWS), cblk, 0, stream>>>(x, xb);
    cvt_m_kernel<<<dim3((KP / 2 + 255) / 256, NP),    cblk, 0, stream>>>(M, mb);

    gemm_bt_kernel<<<dim3(NP / 128, MROWS / 128), dim3(256), 0, stream>>>(xb, mb, out);
}

// Round 3
// 688.109 us; speedup vs baseline: 1.0007x; 1.0007x over previous
//
#include <hip/hip_runtime.h>
#include <cstdint>
#include <cstddef>

// Problem constants
#define MROWS 8192   // B*C = 32*256
#define VIN   6890   // K (real)
#define VOUT  1723   // N (real)
#define KP    6912   // K padded to multiple of 32 (216 * 32)
#define NP    1792   // N padded to multiple of 128 (14 * 128)

typedef __attribute__((ext_vector_type(8))) __bf16 bf16x8;  // 4 VGPRs, A/B frag
typedef __attribute__((ext_vector_type(4))) float f32x4;    // C/D frag

// ---------------- fp32 -> bf16 (RNE) ----------------
__device__ __forceinline__ uint32_t f2bf(float f) {
    uint32_t u = __builtin_bit_cast(uint32_t, f);
    u += 0x7fffu + ((u >> 16) & 1u);
    return u >> 16;
}

// Convert 8 floats/thread: 4x float2 loads (8B-aligned always), one 16B store.
// x: [MROWS][VIN] fp32 -> xb: [MROWS][KP] bf16 (zero-padded K tail)
__global__ __launch_bounds__(256) void cvt_x_kernel(
        const float* __restrict__ x, uint16_t* __restrict__ xb) {
    const int row = blockIdx.y;
    const int g   = blockIdx.x * blockDim.x + threadIdx.x;  // 8-float group
    if (g >= KP / 8) return;
    const int c = g * 8;
    uint32_t w[4];
#pragma unroll
    for (int p = 0; p < 4; ++p) {
        const int cc = c + p * 2;
        float2 f = make_float2(0.f, 0.f);
        if (cc < VIN)  // VIN even -> pair fully valid or fully pad
            f = *(const float2*)(x + (size_t)row * VIN + cc);
        w[p] = f2bf(f.x) | (f2bf(f.y) << 16);
    }
    uint4 o; o.x = w[0]; o.y = w[1]; o.z = w[2]; o.w = w[3];
    *(uint4*)(xb + (size_t)row * KP + c) = o;   // row*KP*2 and c*2 both 16B-multiples
}

// M: [VOUT][VIN] fp32 -> mb: [NP][KP] bf16 (zero-padded rows & K tail)
__global__ __launch_bounds__(256) void cvt_m_kernel(
        const float* __restrict__ m, uint16_t* __restrict__ mb) {
    const int row = blockIdx.y;
    const int g   = blockIdx.x * blockDim.x + threadIdx.x;
    if (g >= KP / 8) return;
    const int c = g * 8;
    uint32_t w[4];
    const bool rv = (row < VOUT);
#pragma unroll
    for (int p = 0; p < 4; ++p) {
        const int cc = c + p * 2;
        float2 f = make_float2(0.f, 0.f);
        if (rv && cc < VIN)
            f = *(const float2*)(m + (size_t)row * VIN + cc);
        w[p] = f2bf(f.x) | (f2bf(f.y) << 16);
    }
    uint4 o; o.x = w[0]; o.y = w[1]; o.z = w[2]; o.w = w[3];
    *(uint4*)(mb + (size_t)row * KP + c) = o;
}

// ---------------- async global -> LDS, 16B/lane ----------------
__device__ __forceinline__ void gload_lds16(const void* g, void* l) {
    __builtin_amdgcn_global_load_lds(
        (const __attribute__((address_space(1))) void*)g,
        (__attribute__((address_space(3))) void*)l,
        16, 0, 0);
}

// ---------------- bf16 MFMA GEMM: C[m,n] = sum_k X[m,k] * W[n,k] ----------------
// m97 structure: 128x128 tile, 4 waves in 2x2, each wave 4x4 of 16x16x32 MFMA,
// BK=32 staging via global_load_lds (16B), 2-barrier K-loop.
//
// LDS bank-conflict swizzle: within each 16-row staging chunk, the 16B granule
// column is stored at b' = b ^ ((row16>>1)&3). global_load_lds forces LDS dest
// = base + lane*16 (contiguous), but the SOURCE address per lane is free, so
// the swizzle is applied by permuting which global granule each lane fetches.
// ds_read side applies the same XOR. Result: a[i]/b[j] reads spread lanes 0-7
// across 8 distinct bank-quads (2-way aliasing overall = free) instead of 8-way.
__global__ __launch_bounds__(256) void gemm_bt_kernel(
        const uint16_t* __restrict__ X,    // [MROWS][KP] bf16 bits
        const uint16_t* __restrict__ W,    // [NP][KP]   bf16 bits
        float* __restrict__ out) {         // [MROWS][VOUT] fp32
    __shared__ uint16_t lsA[128 * 32];  // 8 KB
    __shared__ uint16_t lsB[128 * 32];  // 8 KB

    const int t    = threadIdx.x;
    const int wave = t >> 6;
    const int lane = t & 63;
    const int wm   = wave >> 1;   // 0..1
    const int wn   = wave & 1;    // 0..1
    const int bm   = blockIdx.y;  // 0..63  (M tiles)
    const int bn   = blockIdx.x;  // 0..13  (N tiles)

    // staging coords: 256 threads cover 64 rows x 64 bytes per issue
    const int srow  = t >> 2;                         // 0..63 (global tile row)
    const int row16 = srow & 15;                      // row within wave's 16-row chunk
    const int sbyte = ((t & 3) ^ ((row16 >> 1) & 3)) * 16;  // swizzled granule

    const char* gA = (const char*)(X + (size_t)(bm * 128 + srow) * KP) + sbyte;
    const char* gB = (const char*)(W + (size_t)(bn * 128 + srow) * KP) + sbyte;
    const size_t gRow64 = (size_t)64 * KP * 2;  // 64 rows in bytes

    // wave-uniform LDS bases (global_load_lds scatters at base + lane*16)
    uint16_t* lA0 = &lsA[wave * 512];
    uint16_t* lA1 = &lsA[2048 + wave * 512];
    uint16_t* lB0 = &lsB[wave * 512];
    uint16_t* lB1 = &lsB[2048 + wave * 512];

    // compute coords (16x16x32 A/B frag: row/col = lane&15, k = (lane>>4)*8 + j)
    const int m15  = lane & 15;
    const int gsel = ((lane >> 4) ^ ((m15 >> 1) & 3)) * 8;   // swizzled ushort offset

    f32x4 acc[4][4] = {};

    for (int kb = 0; kb < KP / 32; ++kb) {
        const size_t koff = (size_t)kb * 64;  // bytes
        gload_lds16(gA + koff,          lA0);
        gload_lds16(gA + gRow64 + koff, lA1);
        gload_lds16(gB + koff,          lB0);
        gload_lds16(gB + gRow64 + koff, lB1);
        __syncthreads();  // compiler emits s_waitcnt vmcnt(0) before s_barrier

        bf16x8 a[4], b[4];
#pragma unroll
        for (int i = 0; i < 4; ++i) {
            a[i] = *(const bf16x8*)&lsA[(wm * 64 + i * 16 + m15) * 32 + gsel];
            b[i] = *(const bf16x8*)&lsB[(wn * 64 + i * 16 + m15) * 32 + gsel];
        }
#pragma unroll
        for (int i = 0; i < 4; ++i)
#pragma unroll
            for (int j = 0; j < 4; ++j)
                acc[i][j] = __builtin_amdgcn_mfma_f32_16x16x32_bf16(
                    a[i], b[j], acc[i][j], 0, 0, 0);
        __syncthreads();
    }

    // epilogue: C/D layout col = lane&15, row = (lane>>4)*4 + reg  [m89/m91 verified]
    const int row0 = bm * 128 + wm * 64 + (lane >> 4) * 4;
    const int col0 = bn * 128 + wn * 64 + m15;
#pragma unroll
    for (int j = 0; j < 4; ++j) {
        const int col = col0 + j * 16;
        if (col < VOUT) {
#pragma unroll
            for (int i = 0; i < 4; ++i) {
                const int rowb = row0 + i * 16;
#pragma unroll
                for (int r = 0; r < 4; ++r)
                    out[(size_t)(rowb + r) * VOUT + col] = acc[i][j][r];
            }
        }
    }
}

// ---------------- fp32 fallback (only if ws too small) ----------------
__global__ void fallback_kernel(const float* __restrict__ x,
                                const float* __restrict__ M,
                                float* __restrict__ out) {
    const int m = blockIdx.y;
    const int o = blockIdx.x * blockDim.x + threadIdx.x;
    if (o >= VOUT) return;
    const float* xr = x + (size_t)m * VIN;
    const float* mr = M + (size_t)o * VIN;
    float s = 0.f;
    for (int k = 0; k < VIN; ++k) s = fmaf(xr[k], mr[k], s);
    out[(size_t)m * VOUT + o] = s;
}

extern "C" void kernel_launch(void* const* d_in, const int* in_sizes, int n_in,
                              void* d_out, int out_size, void* d_ws, size_t ws_size,
                              hipStream_t stream) {
    const float* x = (const float*)d_in[0];
    const float* M = (const float*)d_in[1];
    float* out = (float*)d_out;

    const size_t need = ((size_t)MROWS * KP + (size_t)NP * KP) * sizeof(uint16_t);
    if (ws_size < need) {
        // emergency correct-but-slow path
        fallback_kernel<<<dim3((VOUT + 255) / 256, MROWS), dim3(256), 0, stream>>>(x, M, out);
        return;
    }

    uint16_t* xb = (uint16_t*)d_ws;
    uint16_t* mb = xb + (size_t)MROWS * KP;

    const dim3 cblk(256);
    const int gx = (KP / 8 + 255) / 256;  // 4
    cvt_x_kernel<<<dim3(gx, MROWS), cblk, 0, stream>>>(x, xb);
    cvt_m_kernel<<<dim3(gx, NP),    cblk, 0, stream>>>(M, mb);

    gemm_bt_kernel<<<dim3(NP / 128, MROWS / 128), dim3(256), 0, stream>>>(xb, mb, out);
}